// Round 8
// baseline (152.468 us; speedup 1.0000x reference)
//
#include <hip/hip_runtime.h>

// H=16, DK=DV=64, D=1024, N=M=2048.
// scores[h,n,m] = ((A_h^T q_n + vh_h) . k_m)/8 + row-consts (drop in softmax),
//   A_h[i][j] = sum_d Wq[h,i,d]*Wk[h,j,d],  vh_h[j] = sum_d Wk[h,j,d]*bq[h,d].
// pooled[d] = sum_h sum_v r_h[v]*Wv[h,v,d] + 2048*sum_h bv[h,d],
//   r_h[v] = sum_n softmax_row . V[:,v].   out = pooled @ Wo^T + bo.
// No max-tracking softmax: |s|max ~ 27 << 88 -> exp safe in fp32.
//
// v8: fixes v7's measured LDS wall (4.8M bank-conflict cycles = ~590cy/CU-step):
//  (1) K/V LDS tiles: linear [64][64] bf16 + XOR swizzle byte^((row&7)<<4)
//      on write AND read (stride-72 rows made ds_read_b128 ~8-way conflicted).
//  (2) 32 q-rows/wave (v3's two-tile S0/S1 math): K/V frag reads amortize
//      over 2x MFMA -> LDS volume per work halves.
//  (3) 4 waves x 128 rows, grid (16,16): 4-wave barrier, P stride 76 (v3's
//      proven-low-conflict P layout).

typedef __attribute__((ext_vector_type(4))) float floatx4;
typedef __attribute__((ext_vector_type(8))) short shortx8;

__device__ inline unsigned short f2bf(float f) {
    unsigned int u = __float_as_uint(f);
    u += 0x7FFFu + ((u >> 16) & 1u);   // RNE
    return (unsigned short)(u >> 16);
}
__device__ inline float bf2f(unsigned short s) {
    return __uint_as_float(((unsigned int)s) << 16);
}

// byte offset into a [64][64]-bf16 LDS tile, bank-conflict-free:
// row*128 + (bytecol ^ ((row&7)<<4)); bijective per row (16B-granule XOR).
#define SWZ(row, bc) ((row) * 128 + ((bc) ^ (((row) & 7) << 4)))

// =================== prep: fused A-partials / K-cvt / V-transpose ============
// grid 176: blocks 0-127: (g,h) A-partial + vh-partial via MFMA (k-chunk 128)
//           blocks 128-143: K bf16 convert (linear) + r zero
//           blocks 144-175: V transpose -> VT bf16 (linear [64][2048])
__global__ __launch_bounds__(256) void prep_kernel(
    const float* __restrict__ Wq, const float* __restrict__ Wk,
    const float* __restrict__ bq, const float* __restrict__ keys,
    const float* __restrict__ values,
    float* __restrict__ Apart, float* __restrict__ vhpart,
    unsigned short* __restrict__ Kb, unsigned short* __restrict__ VT,
    float* __restrict__ r_ws) {
    const int tid = threadIdx.x;
    const int bx = blockIdx.x;
    __shared__ __align__(16) unsigned char sm[36352];
    if (bx < 128) {
        const int g = bx >> 4, h = bx & 15;
        const int c0 = g * 128;
        unsigned short* wq = (unsigned short*)sm;            // 64*136 ushort
        unsigned short* wk = (unsigned short*)(sm + 17408);  // 64*136 ushort
        float* bqs = (float*)(sm + 34816);                   // 128
        float* vred = (float*)(sm + 35328);                  // 4*64
        {
            int row = tid >> 2, cs = (tid & 3) * 32;
            const float* wqp = Wq + (size_t)(h * 64 + row) * 1024 + c0 + cs;
            const float* wkp = Wk + (size_t)(h * 64 + row) * 1024 + c0 + cs;
            #pragma unroll
            for (int u = 0; u < 8; ++u) {
                float4 a = *(const float4*)&wqp[u * 4];
                float4 b = *(const float4*)&wkp[u * 4];
                *(ushort4*)&wq[row * 136 + cs + u * 4] =
                    (ushort4){f2bf(a.x), f2bf(a.y), f2bf(a.z), f2bf(a.w)};
                *(ushort4*)&wk[row * 136 + cs + u * 4] =
                    (ushort4){f2bf(b.x), f2bf(b.y), f2bf(b.z), f2bf(b.w)};
            }
            if (tid < 128) bqs[tid] = bq[h * 1024 + c0 + tid];
        }
        __syncthreads();
        const int w = tid >> 6, lane = tid & 63;
        const int ln = lane & 15, quad = lane >> 4;
        {   // vh partial
            const int j = tid & 63, half = tid >> 6;
            float accv = 0.f;
            #pragma unroll
            for (int u = 0; u < 32; ++u)
                accv += bf2f(wk[j * 136 + half * 32 + u]) * bqs[half * 32 + u];
            vred[half * 64 + j] = accv;
        }
        // A-tile: wave w -> rows w*16..+15
        shortx8 af[4];
        #pragma unroll
        for (int kk = 0; kk < 4; ++kk)
            af[kk] = *(shortx8*)&wq[(w * 16 + ln) * 136 + kk * 32 + quad * 8];
        float* ap = Apart + (size_t)bx * 4096;
        #pragma unroll
        for (int cn = 0; cn < 4; ++cn) {
            floatx4 acc = {};
            #pragma unroll
            for (int kk = 0; kk < 4; ++kk) {
                shortx8 bf_ = *(shortx8*)&wk[(cn * 16 + ln) * 136 + kk * 32 + quad * 8];
                acc = __builtin_amdgcn_mfma_f32_16x16x32_bf16(af[kk], bf_, acc, 0, 0, 0);
            }
            #pragma unroll
            for (int r = 0; r < 4; ++r)
                ap[(w * 16 + quad * 4 + r) * 64 + cn * 16 + ln] = acc[r];
        }
        __syncthreads();
        if (tid < 64)
            vhpart[bx * 64 + tid] = vred[tid] + vred[64 + tid] +
                                    vred[128 + tid] + vred[192 + tid];
    } else if (bx < 144) {
        int bk = bx - 128;
        int base = (bk * 256 + tid) * 32;
        #pragma unroll
        for (int u = 0; u < 8; ++u) {
            float4 a = *(const float4*)&keys[base + u * 4];
            *(ushort4*)&Kb[base + u * 4] =
                (ushort4){f2bf(a.x), f2bf(a.y), f2bf(a.z), f2bf(a.w)};
        }
        if (tid < 64) r_ws[bk * 64 + tid] = 0.f;
    } else {
        int bb = bx - 144, m0 = bb * 64;
        unsigned short* vts = (unsigned short*)sm;   // 64*72 ushort
        #pragma unroll
        for (int it = 0; it < 4; ++it) {
            int gi = tid + it * 256;
            int m = gi >> 4, c4 = (gi & 15) * 4;
            float4 a = *(const float4*)&values[(size_t)(m0 + m) * 64 + c4];
            vts[(c4 + 0) * 72 + m] = f2bf(a.x);
            vts[(c4 + 1) * 72 + m] = f2bf(a.y);
            vts[(c4 + 2) * 72 + m] = f2bf(a.z);
            vts[(c4 + 3) * 72 + m] = f2bf(a.w);
        }
        __syncthreads();
        #pragma unroll
        for (int it = 0; it < 2; ++it) {
            int gi = tid + it * 256;
            int v = gi >> 3, seg = (gi & 7) * 8;
            *(shortx8*)&VT[v * 2048 + m0 + seg] = *(shortx8*)&vts[v * 72 + seg];
        }
    }
}

// =================== reduceA: sum 8 A-partials -> Atlg (A^T, bf16), vhg ======
__global__ __launch_bounds__(256) void reduceA_kernel(
    const float* __restrict__ Apart, const float* __restrict__ vhpart,
    unsigned short* __restrict__ Atlg, float* __restrict__ vhg) {
    const int tid = threadIdx.x;
    const int h = blockIdx.x >> 2, uq = blockIdx.x & 3;
    #pragma unroll
    for (int uu = 0; uu < 4; ++uu) {
        int e = (uq * 4 + uu) * 256 + tid;     // e = i*64 + j
        float s = 0.f;
        #pragma unroll
        for (int g = 0; g < 8; ++g)
            s += Apart[g * 65536 + h * 4096 + e];
        Atlg[h * 4096 + (e & 63) * 64 + (e >> 6)] = f2bf(s);   // A^T[j][i]
    }
    if (uq == 0 && tid < 64) {
        float s = 0.f;
        #pragma unroll
        for (int g = 0; g < 8; ++g) s += vhpart[(g * 16 + h) * 64 + tid];
        vhg[h * 64 + tid] = s;
    }
}

// =================== flash v8: grid (16 qtiles of 128 rows, 16 h) ============
// 256 threads = 4 waves; wave w owns rows n0+w*32..+31 (two 16-row tiles).
// 32 steps of 64 keys. K/V tiles ([64][64] bf16, XOR-swizzled) staged into
// dbuf LDS by all threads, consumed by all 4 waves. 1 barrier/step.
#define QSCALE 0.18033688f   /* 0.125 * log2(e) */
__global__ __launch_bounds__(256, 1) void flash_kernel(
    const float* __restrict__ queries, const unsigned short* __restrict__ Atlg,
    const float* __restrict__ vhg, const unsigned short* __restrict__ Kb,
    const unsigned short* __restrict__ VT, float* __restrict__ r_ws) {
    const int h = blockIdx.y;
    const int n0 = blockIdx.x * 128;
    const int tid = threadIdx.x;
    const int w = tid >> 6, lane = tid & 63;
    const int ln = lane & 15, quad = lane >> 4;

    __shared__ __align__(16) unsigned char lds[70656];
    __shared__ float vhs[64];
    // main loop: Kbuf[2] @0/@8192 ; Vbuf[2] @16384/@24576 ; qh @32768
    //            ([128][72] shorts = 18432B, ends 51200);
    //            Pw @51200 + w*4864 ([32][76] shorts per wave, ends 70656)
    // phase A/B: qstage @0 ([128][72]=18432B), Atl @18432 (9216B): both live
    //            only before the staging prologue (barrier-ordered).
    // epilogue:  Rred @0 (4*64 f32) after final barrier.
    unsigned short* qh = (unsigned short*)(lds + 32768);
    unsigned short* Pw = (unsigned short*)(lds + 51200 + w * 4864);
    unsigned short* qstage = (unsigned short*)lds;
    unsigned short* Atl = (unsigned short*)(lds + 18432);
    float* Rred = (float*)lds;

    // ---- phase A: stage queries (bf16) [128][72], Atl (8KB coalesced), vhs -
    #pragma unroll
    for (int it = 0; it < 2; ++it) {
        int gi = tid + it * 256;
        int row = gi >> 2, c16 = (gi & 3) * 16;
        const float* qp = queries + (size_t)(n0 + row) * 64 + c16;
        #pragma unroll
        for (int u = 0; u < 4; ++u) {
            float4 a = *(const float4*)&qp[u * 4];
            *(ushort4*)&qstage[row * 72 + c16 + u * 4] =
                (ushort4){f2bf(a.x), f2bf(a.y), f2bf(a.z), f2bf(a.w)};
        }
    }
    #pragma unroll
    for (int it = 0; it < 2; ++it) {
        int gi = tid + it * 256;
        int row = gi >> 3, off = (gi & 7) * 8;
        *(shortx8*)&Atl[row * 72 + off] =
            *(const shortx8*)&Atlg[h * 4096 + row * 64 + off];
    }
    if (tid < 64) vhs[tid] = vhg[h * 64 + tid];
    __syncthreads();

    // ---- phase B: qhat = (q.A^T + vh)*scale; wave w -> rows w*32..+31 ------
    #pragma unroll
    for (int t2 = 0; t2 < 2; ++t2) {
        const int tt = w * 2 + t2;               // 16-row tile index 0..7
        shortx8 qa[2];
        #pragma unroll
        for (int kk = 0; kk < 2; ++kk)
            qa[kk] = *(shortx8*)&qstage[(tt * 16 + ln) * 72 + kk * 32 + quad * 8];
        #pragma unroll
        for (int cn = 0; cn < 4; ++cn) {
            floatx4 acc = {};
            #pragma unroll
            for (int kk = 0; kk < 2; ++kk) {
                shortx8 bfr = *(shortx8*)&Atl[(cn * 16 + ln) * 72 + kk * 32 + quad * 8];
                acc = __builtin_amdgcn_mfma_f32_16x16x32_bf16(qa[kk], bfr, acc, 0, 0, 0);
            }
            #pragma unroll
            for (int r = 0; r < 4; ++r)
                qh[(tt * 16 + quad * 4 + r) * 72 + cn * 16 + ln] =
                    f2bf((acc[r] + vhs[cn * 16 + ln]) * QSCALE);
        }
    }
    __syncthreads();   // qstage/Atl dead; qh published

    // ---- prologue: qf regs; stage step-0 K/V tiles (swizzled) --------------
    shortx8 qf[2][2];
    #pragma unroll
    for (int t2 = 0; t2 < 2; ++t2)
        #pragma unroll
        for (int kk = 0; kk < 2; ++kk)
            qf[t2][kk] = *(shortx8*)&qh[((w * 2 + t2) * 16 + ln) * 72 + kk * 32 + quad * 8];

    const int srow = tid >> 2;                 // 0..63 (tile row)
    const int sc = (tid & 3) * 16;             // col offset in shorts (2x16B)
    {
        unsigned char* kb0 = lds;              // Kbuf[0]
        unsigned char* vb0 = lds + 16384;      // Vbuf[0]
        #pragma unroll
        for (int i = 0; i < 2; ++i) {
            shortx8 kr = *(const shortx8*)&Kb[(size_t)srow * 64 + sc + i * 8];
            shortx8 vr = *(const shortx8*)&VT[(size_t)srow * 2048 + sc + i * 8];
            *(shortx8*)(kb0 + SWZ(srow, sc * 2 + i * 16)) = kr;
            *(shortx8*)(vb0 + SWZ(srow, sc * 2 + i * 16)) = vr;
        }
    }
    __syncthreads();

    // ---- main loop: 32 steps of 64 keys, 1 barrier/step --------------------
    floatx4 O0[4] = {}, O1[4] = {};
    float lacc0[4] = {}, lacc1[4] = {};
    for (int s = 0; s < 32; ++s) {
        const int b = s & 1;
        const unsigned char* kb = lds + b * 8192;
        const unsigned char* vb = lds + 16384 + b * 8192;
        // issue next-step staging loads (consumed at step end)
        shortx8 krn[2], vrn[2];
        if (s < 31) {
            int m0n = (s + 1) * 64;
            #pragma unroll
            for (int i = 0; i < 2; ++i) {
                krn[i] = *(const shortx8*)&Kb[(size_t)(m0n + srow) * 64 + sc + i * 8];
                vrn[i] = *(const shortx8*)&VT[(size_t)srow * 2048 + m0n + sc + i * 8];
            }
        }
        // QK: S[t][cm], K frags shared across both row-tiles
        floatx4 S0[4], S1[4];
        #pragma unroll
        for (int cm = 0; cm < 4; ++cm) {
            shortx8 kf0 = *(const shortx8*)(kb + SWZ(cm * 16 + ln, quad * 16));
            shortx8 kf1 = *(const shortx8*)(kb + SWZ(cm * 16 + ln, 64 + quad * 16));
            floatx4 a0 = {}, a1 = {};
            a0 = __builtin_amdgcn_mfma_f32_16x16x32_bf16(qf[0][0], kf0, a0, 0, 0, 0);
            a0 = __builtin_amdgcn_mfma_f32_16x16x32_bf16(qf[0][1], kf1, a0, 0, 0, 0);
            a1 = __builtin_amdgcn_mfma_f32_16x16x32_bf16(qf[1][0], kf0, a1, 0, 0, 0);
            a1 = __builtin_amdgcn_mfma_f32_16x16x32_bf16(qf[1][1], kf1, a1, 0, 0, 0);
            S0[cm] = a0; S1[cm] = a1;
        }
        // exp2 + P (wave-private LDS, stride 76)
        #pragma unroll
        for (int cm = 0; cm < 4; ++cm) {
            #pragma unroll
            for (int r = 0; r < 4; ++r) {
                float p0 = __builtin_amdgcn_exp2f(S0[cm][r]); lacc0[r] += p0;
                Pw[(quad * 4 + r) * 76 + cm * 16 + ln] = f2bf(p0);
                float p1 = __builtin_amdgcn_exp2f(S1[cm][r]); lacc1[r] += p1;
                Pw[(16 + quad * 4 + r) * 76 + cm * 16 + ln] = f2bf(p1);
            }
        }
        // P frags (same wave wrote them: lgkm ordering, no barrier)
        shortx8 pf[2][2];
        #pragma unroll
        for (int t2 = 0; t2 < 2; ++t2)
            #pragma unroll
            for (int kk = 0; kk < 2; ++kk)
                pf[t2][kk] = *(shortx8*)&Pw[(t2 * 16 + ln) * 76 + kk * 32 + quad * 8];
        // PV: V frags shared across both row-tiles
        #pragma unroll
        for (int cv = 0; cv < 4; ++cv) {
            shortx8 v0 = *(const shortx8*)(vb + SWZ(cv * 16 + ln, quad * 16));
            shortx8 v1 = *(const shortx8*)(vb + SWZ(cv * 16 + ln, 64 + quad * 16));
            O0[cv] = __builtin_amdgcn_mfma_f32_16x16x32_bf16(pf[0][0], v0, O0[cv], 0, 0, 0);
            O0[cv] = __builtin_amdgcn_mfma_f32_16x16x32_bf16(pf[0][1], v1, O0[cv], 0, 0, 0);
            O1[cv] = __builtin_amdgcn_mfma_f32_16x16x32_bf16(pf[1][0], v0, O1[cv], 0, 0, 0);
            O1[cv] = __builtin_amdgcn_mfma_f32_16x16x32_bf16(pf[1][1], v1, O1[cv], 0, 0, 0);
        }
        // publish next-step tiles into the other buffer, then barrier
        if (s < 31) {
            unsigned char* kbn = lds + (b ^ 1) * 8192;
            unsigned char* vbn = lds + 16384 + (b ^ 1) * 8192;
            #pragma unroll
            for (int i = 0; i < 2; ++i) {
                *(shortx8*)(kbn + SWZ(srow, sc * 2 + i * 16)) = krn[i];
                *(shortx8*)(vbn + SWZ(srow, sc * 2 + i * 16)) = vrn[i];
            }
        }
        __syncthreads();
    }

    // ---- epilogue: wave-local row sums + normalize + r accumulate ----------
    float linv0[4], linv1[4];
    #pragma unroll
    for (int r = 0; r < 4; ++r) {
        float x0 = lacc0[r], x1 = lacc1[r];
        #pragma unroll
        for (int o = 1; o <= 8; o <<= 1) { x0 += __shfl_xor(x0, o); x1 += __shfl_xor(x1, o); }
        linv0[r] = 1.0f / x0;    // row (w*2)*16 + quad*4+r full sum
        linv1[r] = 1.0f / x1;    // row (w*2+1)*16 + quad*4+r
    }
    float sacc[4];
    #pragma unroll
    for (int cv = 0; cv < 4; ++cv) {
        float s = 0.f;
        #pragma unroll
        for (int r = 0; r < 4; ++r)
            s += O0[cv][r] * linv0[r] + O1[cv][r] * linv1[r];
        s += __shfl_xor(s, 16);
        s += __shfl_xor(s, 32);
        sacc[cv] = s;            // sum over the wave's 32 rows, col cv*16+ln
    }
    __syncthreads();             // K/V/P buffers dead -> Rred overlay
    if (quad == 0) {
        #pragma unroll
        for (int cv = 0; cv < 4; ++cv)
            Rred[w * 64 + cv * 16 + ln] = sacc[cv];
    }
    __syncthreads();
    if (tid < 64) {
        float s = Rred[tid] + Rred[64 + tid] + Rred[128 + tid] + Rred[192 + tid];
        atomicAdd(&r_ws[h * 64 + tid], s);
    }
}

// =================== pool: pooled[d] = 2048*sum_h bv + sum_hv r*Wv ----------
__global__ __launch_bounds__(256) void pool_kernel(
    const float* __restrict__ Wv, const float* __restrict__ bv,
    const float* __restrict__ r_ws, float* __restrict__ pooled) {
    const int tid = threadIdx.x;
    const int d0 = blockIdx.x * 16;       // grid 64
    const int d = tid & 15, hh = tid >> 4;
    __shared__ float red[16][17];
    float acc = bv[hh * 1024 + d0 + d] * 2048.0f;
    const float* rv = r_ws + hh * 64;
    const float* wp = Wv + (size_t)hh * 64 * 1024 + d0 + d;
    #pragma unroll 8
    for (int v = 0; v < 64; ++v) acc += rv[v] * wp[(size_t)v * 1024];
    red[hh][d] = acc;
    __syncthreads();
    if (tid < 16) {
        float s = 0.f;
        #pragma unroll
        for (int g = 0; g < 16; ++g) s += red[g][tid];
        pooled[d0 + tid] = s;
    }
}

// =================== out: out[dp] = pooled . Wo[dp,:] + bo[dp] ---------------
__global__ __launch_bounds__(256) void out_kernel(
    const float* __restrict__ Wo, const float* __restrict__ bo,
    const float* __restrict__ pooled, float* __restrict__ out) {
    const int tid = threadIdx.x, w = tid >> 6, lane = tid & 63;
    const int dp = blockIdx.x * 4 + w;    // grid 256
    const float* wr = Wo + (size_t)dp * 1024 + lane * 16;
    const float* pp = pooled + lane * 16;
    float acc = 0.f;
    #pragma unroll
    for (int u = 0; u < 4; ++u) {
        float4 a = *(const float4*)&wr[u * 4];
        float4 p = *(const float4*)&pp[u * 4];
        acc += a.x * p.x + a.y * p.y + a.z * p.z + a.w * p.w;
    }
    #pragma unroll
    for (int o = 32; o > 0; o >>= 1) acc += __shfl_xor(acc, o);
    if (lane == 0) out[dp] = acc + bo[dp];
}

extern "C" void kernel_launch(void* const* d_in, const int* in_sizes, int n_in,
                              void* d_out, int out_size, void* d_ws, size_t ws_size,
                              hipStream_t stream) {
    const float* queries = (const float*)d_in[0];
    const float* keys    = (const float*)d_in[1];
    const float* values  = (const float*)d_in[2];
    const float* Wq      = (const float*)d_in[3];
    const float* bq      = (const float*)d_in[4];
    const float* Wk      = (const float*)d_in[5];
    // d_in[6] = bk: row-constant under softmax, unused
    const float* Wv      = (const float*)d_in[7];
    const float* bv      = (const float*)d_in[8];
    const float* Wo      = (const float*)d_in[9];
    const float* bo      = (const float*)d_in[10];
    float* out = (float*)d_out;

    float* Apart  = (float*)d_ws;                 // 128*4096 floats
    float* vhpart = Apart + 524288;               // 128*64
    float* r_ws   = vhpart + 8192;                // 1024
    float* pooled = r_ws + 1024;                  // 1024
    unsigned short* Kb = (unsigned short*)(pooled + 1024);  // 2048*64 bf16
    unsigned short* VT = Kb + 131072;                       // 64*2048 bf16
    unsigned short* Atlg = VT + 131072;                     // 16*64*64 bf16
    float* vhg = (float*)(Atlg + 65536);                    // 16*64
    // total ws: ~2.8 MB

    prep_kernel<<<176, 256, 0, stream>>>(Wq, Wk, bq, keys, values,
                                         Apart, vhpart, Kb, VT, r_ws);
    reduceA_kernel<<<64, 256, 0, stream>>>(Apart, vhpart, Atlg, vhg);
    flash_kernel<<<dim3(16, 16), 256, 0, stream>>>(queries, Atlg, vhg,
                                                   Kb, VT, r_ws);
    pool_kernel<<<64, 256, 0, stream>>>(Wv, bv, r_ws, pooled);
    out_kernel<<<256, 256, 0, stream>>>(Wo, bo, pooled, out);
}

// Round 9
// 137.678 us; speedup vs baseline: 1.1074x; 1.1074x over previous
//
#include <hip/hip_runtime.h>

// H=16, DK=DV=64, D=1024, N=M=2048.
// scores[h,n,m] = ((A_h^T q_n + vh_h) . k_m)/8 + row-consts (drop in softmax),
//   A_h[i][j] = sum_d Wq[h,i,d]*Wk[h,j,d],  vh_h[j] = sum_d Wk[h,j,d]*bq[h,d].
// KEY IDENTITY (v9): pooled needs only r_h[v] = sum_n sum_m attn[n,m]*values[m,v]
//   = sum_m g_h[m]*values[m,v],  g_h[m] = sum_n exp(s[n,m]) / l[n],
//   l[n] = sum_m exp(s[n,m]).
// -> TWO QK-only passes (same total MFMA as QK+PV, but NO P round-trip, NO V
//    staging, NO per-row O): pass1 computes u=1/l (row sums), pass2 recomputes
//    scores, reduces exp*u over n into g, folds g.values into r in-epilogue.
// Both passes: 64-row/64-key blocks -> grid (32,16)=512 = 2 blocks/CU
// (v8's fatal flaw was grid 256 = 1 wave/SIMD). v8's swizzle kept (conflicts
// 4.8M->98K proven). No max-tracking: |s|max ~27 -> exp2 safe in fp32.

typedef __attribute__((ext_vector_type(4))) float floatx4;
typedef __attribute__((ext_vector_type(8))) short shortx8;

__device__ inline unsigned short f2bf(float f) {
    unsigned int u = __float_as_uint(f);
    u += 0x7FFFu + ((u >> 16) & 1u);   // RNE
    return (unsigned short)(u >> 16);
}
__device__ inline float bf2f(unsigned short s) {
    return __uint_as_float(((unsigned int)s) << 16);
}

// byte offset into a [64][64]-bf16 LDS tile, bank-conflict-free (v8-proven):
#define SWZ(row, bc) ((row) * 128 + ((bc) ^ (((row) & 7) << 4)))
#define QSCALE 0.18033688f   /* 0.125 * log2(e) */

// =================== prep: fused A-partials / K-cvt =========================
// grid 144: blocks 0-127: (g,h) A-partial + vh-partial via MFMA (k-chunk 128)
//           blocks 128-143: K bf16 convert (linear) + r zero
__global__ __launch_bounds__(256) void prep_kernel(
    const float* __restrict__ Wq, const float* __restrict__ Wk,
    const float* __restrict__ bq, const float* __restrict__ keys,
    float* __restrict__ Apart, float* __restrict__ vhpart,
    unsigned short* __restrict__ Kb, float* __restrict__ r_ws) {
    const int tid = threadIdx.x;
    const int bx = blockIdx.x;
    __shared__ __align__(16) unsigned char sm[36352];
    if (bx < 128) {
        const int g = bx >> 4, h = bx & 15;
        const int c0 = g * 128;
        unsigned short* wq = (unsigned short*)sm;            // 64*136 ushort
        unsigned short* wk = (unsigned short*)(sm + 17408);  // 64*136 ushort
        float* bqs = (float*)(sm + 34816);                   // 128
        float* vred = (float*)(sm + 35328);                  // 4*64
        {
            int row = tid >> 2, cs = (tid & 3) * 32;
            const float* wqp = Wq + (size_t)(h * 64 + row) * 1024 + c0 + cs;
            const float* wkp = Wk + (size_t)(h * 64 + row) * 1024 + c0 + cs;
            #pragma unroll
            for (int u = 0; u < 8; ++u) {
                float4 a = *(const float4*)&wqp[u * 4];
                float4 b = *(const float4*)&wkp[u * 4];
                *(ushort4*)&wq[row * 136 + cs + u * 4] =
                    (ushort4){f2bf(a.x), f2bf(a.y), f2bf(a.z), f2bf(a.w)};
                *(ushort4*)&wk[row * 136 + cs + u * 4] =
                    (ushort4){f2bf(b.x), f2bf(b.y), f2bf(b.z), f2bf(b.w)};
            }
            if (tid < 128) bqs[tid] = bq[h * 1024 + c0 + tid];
        }
        __syncthreads();
        const int w = tid >> 6, lane = tid & 63;
        const int ln = lane & 15, quad = lane >> 4;
        {   // vh partial
            const int j = tid & 63, half = tid >> 6;
            float accv = 0.f;
            #pragma unroll
            for (int u = 0; u < 32; ++u)
                accv += bf2f(wk[j * 136 + half * 32 + u]) * bqs[half * 32 + u];
            vred[half * 64 + j] = accv;
        }
        // A-tile: wave w -> rows w*16..+15
        shortx8 af[4];
        #pragma unroll
        for (int kk = 0; kk < 4; ++kk)
            af[kk] = *(shortx8*)&wq[(w * 16 + ln) * 136 + kk * 32 + quad * 8];
        float* ap = Apart + (size_t)bx * 4096;
        #pragma unroll
        for (int cn = 0; cn < 4; ++cn) {
            floatx4 acc = {};
            #pragma unroll
            for (int kk = 0; kk < 4; ++kk) {
                shortx8 bf_ = *(shortx8*)&wk[(cn * 16 + ln) * 136 + kk * 32 + quad * 8];
                acc = __builtin_amdgcn_mfma_f32_16x16x32_bf16(af[kk], bf_, acc, 0, 0, 0);
            }
            #pragma unroll
            for (int r = 0; r < 4; ++r)
                ap[(w * 16 + quad * 4 + r) * 64 + cn * 16 + ln] = acc[r];
        }
        __syncthreads();
        if (tid < 64)
            vhpart[bx * 64 + tid] = vred[tid] + vred[64 + tid] +
                                    vred[128 + tid] + vred[192 + tid];
    } else {
        int bk = bx - 128;
        int base = (bk * 256 + tid) * 32;
        #pragma unroll
        for (int u = 0; u < 8; ++u) {
            float4 a = *(const float4*)&keys[base + u * 4];
            *(ushort4*)&Kb[base + u * 4] =
                (ushort4){f2bf(a.x), f2bf(a.y), f2bf(a.z), f2bf(a.w)};
        }
        if (tid < 64) r_ws[bk * 64 + tid] = 0.f;
    }
}

// =================== reduceA: sum 8 A-partials -> Atlg (A^T, bf16), vhg ======
__global__ __launch_bounds__(256) void reduceA_kernel(
    const float* __restrict__ Apart, const float* __restrict__ vhpart,
    unsigned short* __restrict__ Atlg, float* __restrict__ vhg) {
    const int tid = threadIdx.x;
    const int h = blockIdx.x >> 2, uq = blockIdx.x & 3;
    #pragma unroll
    for (int uu = 0; uu < 4; ++uu) {
        int e = (uq * 4 + uu) * 256 + tid;     // e = i*64 + j
        float s = 0.f;
        #pragma unroll
        for (int g = 0; g < 8; ++g)
            s += Apart[g * 65536 + h * 4096 + e];
        Atlg[h * 4096 + (e & 63) * 64 + (e >> 6)] = f2bf(s);   // A^T[j][i]
    }
    if (uq == 0 && tid < 64) {
        float s = 0.f;
        #pragma unroll
        for (int g = 0; g < 8; ++g) s += vhpart[(g * 16 + h) * 64 + tid];
        vhg[h * 64 + tid] = s;
    }
}

// =================== pass1: u[h,n] = 1/sum_m exp2(qhat.k) ====================
// grid (32 ntiles of 64 rows, 16 h), 256 thr = 4 waves; wave w -> rows
// n0+w*16..+15. Computes qhat (phase A/B), writes Qhs global (for pass2),
// then 32 steps of 64 keys: K-tile staged dbuf+SWZ (v8-proven), QK MFMA,
// exp2, row-sum. No P, no V, no O.
__global__ __launch_bounds__(256, 4) void pass1_kernel(
    const float* __restrict__ queries, const unsigned short* __restrict__ Atlg,
    const float* __restrict__ vhg, const unsigned short* __restrict__ Kb,
    unsigned short* __restrict__ Qhs, float* __restrict__ u_ws) {
    const int h = blockIdx.y;
    const int n0 = blockIdx.x * 64;
    const int tid = threadIdx.x;
    const int w = tid >> 6, lane = tid & 63;
    const int ln = lane & 15, quad = lane >> 4;

    __shared__ __align__(16) unsigned char lds[27648];
    __shared__ float vhs[64];
    // phase A: qstage @0 ([64][72]*2B=9216), Atl @9216 (9216)
    // loop:    Kbuf[2] @0..16384 (SWZ [64][64] each), qh @18432 ([64][72])
    unsigned short* qstage = (unsigned short*)lds;
    unsigned short* Atl = (unsigned short*)(lds + 9216);
    unsigned short* qh = (unsigned short*)(lds + 18432);

    // ---- phase A: stage queries (bf16), Atl (coalesced), vhs ---------------
    {
        int row = tid >> 2, c16 = (tid & 3) * 16;
        const float* qp = queries + (size_t)(n0 + row) * 64 + c16;
        #pragma unroll
        for (int u = 0; u < 4; ++u) {
            float4 a = *(const float4*)&qp[u * 4];
            *(ushort4*)&qstage[row * 72 + c16 + u * 4] =
                (ushort4){f2bf(a.x), f2bf(a.y), f2bf(a.z), f2bf(a.w)};
        }
        #pragma unroll
        for (int u = 0; u < 2; ++u)
            *(shortx8*)&Atl[row * 72 + c16 + u * 8] =
                *(const shortx8*)&Atlg[h * 4096 + row * 64 + c16 + u * 8];
    }
    if (tid < 64) vhs[tid] = vhg[h * 64 + tid];
    __syncthreads();

    // ---- phase B: qhat via MFMA; wave w -> rowtile w -----------------------
    {
        shortx8 qa[2];
        #pragma unroll
        for (int kk = 0; kk < 2; ++kk)
            qa[kk] = *(shortx8*)&qstage[(w * 16 + ln) * 72 + kk * 32 + quad * 8];
        #pragma unroll
        for (int cn = 0; cn < 4; ++cn) {
            floatx4 acc = {};
            #pragma unroll
            for (int kk = 0; kk < 2; ++kk) {
                shortx8 bfr = *(shortx8*)&Atl[(cn * 16 + ln) * 72 + kk * 32 + quad * 8];
                acc = __builtin_amdgcn_mfma_f32_16x16x32_bf16(qa[kk], bfr, acc, 0, 0, 0);
            }
            #pragma unroll
            for (int r = 0; r < 4; ++r)
                qh[(w * 16 + quad * 4 + r) * 72 + cn * 16 + ln] =
                    f2bf((acc[r] + vhs[cn * 16 + ln]) * QSCALE);
        }
    }
    __syncthreads();   // qh published; qstage/Atl dead

    // ---- copy qhat -> global Qhs (for pass2); stage K step 0; qf regs ------
    #pragma unroll
    for (int k = 0; k < 2; ++k) {
        int seg = tid * 2 + k, row = seg >> 3, off = (seg & 7) * 8;
        *(shortx8*)&Qhs[((size_t)h * 2048 + n0 + row) * 64 + off] =
            *(shortx8*)&qh[row * 72 + off];
    }
    const int srow = tid >> 2, sc = (tid & 3) * 16;
    #pragma unroll
    for (int i = 0; i < 2; ++i)
        *(shortx8*)(lds + SWZ(srow, sc * 2 + i * 16)) =
            *(const shortx8*)&Kb[(size_t)srow * 64 + sc + i * 8];
    shortx8 qf[2];
    #pragma unroll
    for (int kk = 0; kk < 2; ++kk)
        qf[kk] = *(shortx8*)&qh[(w * 16 + ln) * 72 + kk * 32 + quad * 8];
    __syncthreads();

    // ---- main loop: 32 steps of 64 keys ------------------------------------
    float lacc[4] = {};
    for (int s = 0; s < 32; ++s) {
        const unsigned char* kb = lds + (s & 1) * 8192;
        shortx8 krn[2];
        if (s < 31) {
            int m0n = (s + 1) * 64;
            #pragma unroll
            for (int i = 0; i < 2; ++i)
                krn[i] = *(const shortx8*)&Kb[(size_t)(m0n + srow) * 64 + sc + i * 8];
        }
        #pragma unroll
        for (int cm = 0; cm < 4; ++cm) {
            shortx8 kf0 = *(const shortx8*)(kb + SWZ(cm * 16 + ln, quad * 16));
            shortx8 kf1 = *(const shortx8*)(kb + SWZ(cm * 16 + ln, 64 + quad * 16));
            floatx4 acc = {};
            acc = __builtin_amdgcn_mfma_f32_16x16x32_bf16(qf[0], kf0, acc, 0, 0, 0);
            acc = __builtin_amdgcn_mfma_f32_16x16x32_bf16(qf[1], kf1, acc, 0, 0, 0);
            #pragma unroll
            for (int r = 0; r < 4; ++r)
                lacc[r] += __builtin_amdgcn_exp2f(acc[r]);
        }
        if (s < 31) {
            unsigned char* kbn = lds + (((s & 1) ^ 1)) * 8192;
            #pragma unroll
            for (int i = 0; i < 2; ++i)
                *(shortx8*)(kbn + SWZ(srow, sc * 2 + i * 16)) = krn[i];
        }
        __syncthreads();
    }

    // ---- epilogue: row sums over ln-group, write u = 1/l -------------------
    #pragma unroll
    for (int r = 0; r < 4; ++r) {
        float x = lacc[r];
        #pragma unroll
        for (int o = 1; o <= 8; o <<= 1) x += __shfl_xor(x, o);
        if (ln == 0)
            u_ws[(size_t)h * 2048 + n0 + w * 16 + quad * 4 + r] = 1.0f / x;
    }
}

// =================== pass2: g[h,m]=sum_n exp2(qhat.k)*u[n]; fold r ==========
// grid (32 mtiles of 64 keys, 16 h), 256 thr = 4 waves; wave w -> key columns
// mb+w*16..+15 (K frags resident in regs). 32 steps of 64 q-rows: Qhs-tile
// staged dbuf+SWZ (+u[64]), QK MFMA, exp2*u accumulated per column. Epilogue
// folds r_part[v] = sum_m g[m]*values[m,v] (f32) and atomicAdds r_ws.
__global__ __launch_bounds__(256, 4) void pass2_kernel(
    const unsigned short* __restrict__ Qhs, const float* __restrict__ u_ws,
    const unsigned short* __restrict__ Kb, const float* __restrict__ values,
    float* __restrict__ r_ws) {
    const int h = blockIdx.y;
    const int mb = blockIdx.x * 64;
    const int tid = threadIdx.x;
    const int w = tid >> 6, lane = tid & 63;
    const int ln = lane & 15, quad = lane >> 4;

    __shared__ __align__(16) unsigned char lds[18176];
    // Qbuf[2] @0..16384 (SWZ [64][64]); u_s[2][64] f32 @16384;
    // g_s[64] f32 @16896; Rred[4][64] f32 @17152
    float* u_sb = (float*)(lds + 16384);
    float* g_s = (float*)(lds + 16896);
    float* Rred = (float*)(lds + 17152);

    // K frags for this wave's 16 columns (resident)
    shortx8 kf[2];
    #pragma unroll
    for (int kk = 0; kk < 2; ++kk)
        kf[kk] = *(const shortx8*)&Kb[(size_t)(mb + w * 16 + ln) * 64 + kk * 32 + quad * 8];

    // stage step 0 (q-rows 0..63) + u
    const int srow = tid >> 2, sc = (tid & 3) * 16;
    #pragma unroll
    for (int i = 0; i < 2; ++i)
        *(shortx8*)(lds + SWZ(srow, sc * 2 + i * 16)) =
            *(const shortx8*)&Qhs[((size_t)h * 2048 + srow) * 64 + sc + i * 8];
    if (tid < 64) u_sb[tid] = u_ws[(size_t)h * 2048 + tid];
    __syncthreads();

    // ---- main loop: 32 steps of 64 q-rows ----------------------------------
    float gacc = 0.f;
    for (int s = 0; s < 32; ++s) {
        const unsigned char* qb = lds + (s & 1) * 8192;
        const float* us = u_sb + (s & 1) * 64;
        shortx8 qrn[2];
        float urn = 0.f;
        if (s < 31) {
            int n0n = (s + 1) * 64;
            #pragma unroll
            for (int i = 0; i < 2; ++i)
                qrn[i] = *(const shortx8*)&Qhs[((size_t)h * 2048 + n0n + srow) * 64 + sc + i * 8];
            if (tid < 64) urn = u_ws[(size_t)h * 2048 + n0n + tid];
        }
        #pragma unroll
        for (int rt = 0; rt < 4; ++rt) {
            shortx8 qa0 = *(const shortx8*)(qb + SWZ(rt * 16 + ln, quad * 16));
            shortx8 qa1 = *(const shortx8*)(qb + SWZ(rt * 16 + ln, 64 + quad * 16));
            floatx4 acc = {};
            acc = __builtin_amdgcn_mfma_f32_16x16x32_bf16(qa0, kf[0], acc, 0, 0, 0);
            acc = __builtin_amdgcn_mfma_f32_16x16x32_bf16(qa1, kf[1], acc, 0, 0, 0);
            #pragma unroll
            for (int r = 0; r < 4; ++r)
                gacc += __builtin_amdgcn_exp2f(acc[r]) * us[rt * 16 + quad * 4 + r];
        }
        if (s < 31) {
            unsigned char* qbn = lds + (((s & 1) ^ 1)) * 8192;
            #pragma unroll
            for (int i = 0; i < 2; ++i)
                *(shortx8*)(qbn + SWZ(srow, sc * 2 + i * 16)) = qrn[i];
            if (tid < 64) u_sb[((s & 1) ^ 1) * 64 + tid] = urn;
        }
        __syncthreads();
    }

    // ---- column totals g_s, then fold r_part = g . values ------------------
    gacc += __shfl_xor(gacc, 16);
    gacc += __shfl_xor(gacc, 32);
    if (quad == 0) g_s[w * 16 + ln] = gacc;   // column m = mb + w*16 + ln
    __syncthreads();
    {
        int grp = tid >> 6, v = tid & 63;
        float acc = 0.f;
        #pragma unroll
        for (int j = 0; j < 16; ++j)
            acc += g_s[grp * 16 + j] *
                   values[(size_t)(mb + grp * 16 + j) * 64 + v];
        Rred[grp * 64 + v] = acc;
    }
    __syncthreads();
    if (tid < 64)
        atomicAdd(&r_ws[h * 64 + tid],
                  Rred[tid] + Rred[64 + tid] + Rred[128 + tid] + Rred[192 + tid]);
}

// =================== pool: pooled[d] = 2048*sum_h bv + sum_hv r*Wv ----------
__global__ __launch_bounds__(256) void pool_kernel(
    const float* __restrict__ Wv, const float* __restrict__ bv,
    const float* __restrict__ r_ws, float* __restrict__ pooled) {
    const int tid = threadIdx.x;
    const int d0 = blockIdx.x * 16;       // grid 64
    const int d = tid & 15, hh = tid >> 4;
    __shared__ float red[16][17];
    float acc = bv[hh * 1024 + d0 + d] * 2048.0f;
    const float* rv = r_ws + hh * 64;
    const float* wp = Wv + (size_t)hh * 64 * 1024 + d0 + d;
    #pragma unroll 8
    for (int v = 0; v < 64; ++v) acc += rv[v] * wp[(size_t)v * 1024];
    red[hh][d] = acc;
    __syncthreads();
    if (tid < 16) {
        float s = 0.f;
        #pragma unroll
        for (int g = 0; g < 16; ++g) s += red[g][tid];
        pooled[d0 + tid] = s;
    }
}

// =================== out: out[dp] = pooled . Wo[dp,:] + bo[dp] ---------------
__global__ __launch_bounds__(256) void out_kernel(
    const float* __restrict__ Wo, const float* __restrict__ bo,
    const float* __restrict__ pooled, float* __restrict__ out) {
    const int tid = threadIdx.x, w = tid >> 6, lane = tid & 63;
    const int dp = blockIdx.x * 4 + w;    // grid 256
    const float* wr = Wo + (size_t)dp * 1024 + lane * 16;
    const float* pp = pooled + lane * 16;
    float acc = 0.f;
    #pragma unroll
    for (int u = 0; u < 4; ++u) {
        float4 a = *(const float4*)&wr[u * 4];
        float4 p = *(const float4*)&pp[u * 4];
        acc += a.x * p.x + a.y * p.y + a.z * p.z + a.w * p.w;
    }
    #pragma unroll
    for (int o = 32; o > 0; o >>= 1) acc += __shfl_xor(acc, o);
    if (lane == 0) out[dp] = acc + bo[dp];
}

extern "C" void kernel_launch(void* const* d_in, const int* in_sizes, int n_in,
                              void* d_out, int out_size, void* d_ws, size_t ws_size,
                              hipStream_t stream) {
    const float* queries = (const float*)d_in[0];
    const float* keys    = (const float*)d_in[1];
    const float* values  = (const float*)d_in[2];
    const float* Wq      = (const float*)d_in[3];
    const float* bq      = (const float*)d_in[4];
    const float* Wk      = (const float*)d_in[5];
    // d_in[6] = bk: row-constant under softmax, unused
    const float* Wv      = (const float*)d_in[7];
    const float* bv      = (const float*)d_in[8];
    const float* Wo      = (const float*)d_in[9];
    const float* bo      = (const float*)d_in[10];
    float* out = (float*)d_out;

    // workspace layout (bytes). Qhs (4MB) overlays Apart+vhpart: Apart/vhpart
    // are dead after reduceA, and pass1 (which writes Qhs) launches after it.
    char* base = (char*)d_ws;
    unsigned short* Qhs = (unsigned short*)base;             // 16*2048*64 bf16 = 4MB
    float* Apart  = (float*)base;                            // 128*4096 f (overlay)
    float* vhpart = Apart + 524288;                          // 128*64 f (overlay)
    float* u_ws   = (float*)(base + 4194304);                // 16*2048 f
    float* r_ws   = (float*)(base + 4325376);                // 1024 f
    float* pooled = (float*)(base + 4329472);                // 1024 f
    unsigned short* Kb   = (unsigned short*)(base + 4333568);  // 2048*64 bf16
    unsigned short* Atlg = (unsigned short*)(base + 4595712);  // 16*64*64 bf16
    float* vhg    = (float*)(base + 4726784);                // 16*64 f
    // total ws: ~4.52 MB

    prep_kernel<<<144, 256, 0, stream>>>(Wq, Wk, bq, keys,
                                         Apart, vhpart, Kb, r_ws);
    reduceA_kernel<<<64, 256, 0, stream>>>(Apart, vhpart, Atlg, vhg);
    pass1_kernel<<<dim3(32, 16), 256, 0, stream>>>(queries, Atlg, vhg,
                                                   Kb, Qhs, u_ws);
    pass2_kernel<<<dim3(32, 16), 256, 0, stream>>>(Qhs, u_ws, Kb, values, r_ws);
    pool_kernel<<<64, 256, 0, stream>>>(Wv, bv, r_ws, pooled);
    out_kernel<<<256, 256, 0, stream>>>(Wo, bo, pooled, out);
}